// Round 5
// baseline (167.540 us; speedup 1.0000x reference)
//
#include <hip/hip_runtime.h>
#include <hip/hip_bf16.h>

#define BATCH 16384
#define DIM   512
#define UNITS 1024
// GAMMA = 0.5 folded into epilogue: out = exp(cross - 0.5*xsq - 0.5*musq)

typedef float v16f __attribute__((ext_vector_type(16)));

// Fused prep: blocks [0,4096): inputs fp32 -> A8 fp8 + xsq (one wave/row).
//             blocks [4096,4112): mu -> B8 fp8 (transposed) + musq.
// xsq/musq computed on ORIGINAL fp32 values (pre-quantization).
__global__ __launch_bounds__(256)
void prep_kernel(const float* __restrict__ in, const float* __restrict__ mu,
                 unsigned char* __restrict__ A8, unsigned char* __restrict__ B8,
                 float* __restrict__ xsq, float* __restrict__ musq) {
    __shared__ float lds[64][65];
    __shared__ float red[64][4];
    const int t = threadIdx.x;
    if (blockIdx.x < BATCH / 4) {
        const int lane = t & 63;
        const int row  = blockIdx.x * 4 + (t >> 6);
        const float4* src = (const float4*)(in + (size_t)row * DIM);
        float4 a = src[lane * 2];
        float4 b = src[lane * 2 + 1];
        float s = a.x * a.x + a.y * a.y + a.z * a.z + a.w * a.w
                + b.x * b.x + b.y * b.y + b.z * b.z + b.w * b.w;
        int lo = __builtin_amdgcn_cvt_pk_fp8_f32(a.x, a.y, 0, false);
        lo     = __builtin_amdgcn_cvt_pk_fp8_f32(a.z, a.w, lo, true);
        int hi = __builtin_amdgcn_cvt_pk_fp8_f32(b.x, b.y, 0, false);
        hi     = __builtin_amdgcn_cvt_pk_fp8_f32(b.z, b.w, hi, true);
        *(int2*)(A8 + (size_t)row * DIM + lane * 8) = make_int2(lo, hi);
        for (int off = 32; off; off >>= 1) s += __shfl_down(s, off, 64);
        if (lane == 0) xsq[row] = s;
    } else {
        const int n0 = (blockIdx.x - BATCH / 4) * 64;
        const int c  = t & 63, r4 = t >> 6;     // load phase
        const int nl = t >> 2, kp = t & 3;      // write phase
        float s = 0.f;
        for (int kc = 0; kc < DIM; kc += 64) {
            __syncthreads();
#pragma unroll
            for (int i = 0; i < 16; i++)
                lds[r4 + i * 4][c] = mu[(size_t)(kc + r4 + i * 4) * UNITS + n0 + c];
            __syncthreads();
            int wr[4];
#pragma unroll
            for (int q = 0; q < 4; q++) {
                float f0 = lds[kp * 16 + q * 4 + 0][nl];
                float f1 = lds[kp * 16 + q * 4 + 1][nl];
                float f2 = lds[kp * 16 + q * 4 + 2][nl];
                float f3 = lds[kp * 16 + q * 4 + 3][nl];
                s += f0 * f0 + f1 * f1 + f2 * f2 + f3 * f3;
                int v = __builtin_amdgcn_cvt_pk_fp8_f32(f0, f1, 0, false);
                wr[q]  = __builtin_amdgcn_cvt_pk_fp8_f32(f2, f3, v, true);
            }
            *(int4*)(B8 + (size_t)(n0 + nl) * DIM + kc + kp * 16) =
                make_int4(wr[0], wr[1], wr[2], wr[3]);
        }
        red[nl][kp] = s;
        __syncthreads();
        if (t < 64) musq[n0 + t] = red[t][0] + red[t][1] + red[t][2] + red[t][3];
    }
}

// Barrier-free register-resident-B RBF GEMM.
// 1024 blocks x 4 waves = 4096 fully independent waves (16/CU at VGPR<=128).
// Wave task: 32 N-cols (B-frag for ALL K=512 held in 64 VGPRs) x 128 M-rows
// (4 chunks of 32). A fragments stream global->VGPR as b64 loads; no LDS,
// no __syncthreads, no global_load_lds => no vmcnt(0) barrier drains. The
// compiler is free to software-pipeline a-loads across the 32-deep MFMA
// chain, and 4 independent waves/SIMD cover L2 latency.
// XCD swizzle: XCD x (= blockIdx%8) covers A rows [x*2048, x*2048+2048)
// (1 MB fp8, L2-resident); B8 (512 KB) is L2-resident everywhere.
// Per-chunk epilogue+store gives 4 staggered store bursts per wave ->
// device-wide store/compute overlap instead of a synchronized tail.
__global__ __launch_bounds__(256, 4)
void rbf_gemm_kernel(const unsigned char* __restrict__ A8,
                     const unsigned char* __restrict__ B8,
                     const float* __restrict__ xsq,
                     const float* __restrict__ musq,
                     float* __restrict__ out) {
    const int t  = threadIdx.x;
    const int l  = t & 63;
    const int w  = t >> 6;          // wave 0..3
    const int ln = l & 31;
    const int h  = l >> 5;          // k-sub-half select (frag layout)

    const int b   = blockIdx.x;     // 1024
    const int x   = b & 7;          // XCD (round-robin dispatch)
    const int q   = b >> 3;         // 0..127 within XCD
    const int rg  = q & 15;         // 16 rowgroups of 128 -> 2048 rows/XCD
    const int cgq = q >> 4;         // 0..7
    const int m0  = x * 2048 + rg * 128;
    const int n0  = (cgq * 4 + w) * 32;   // wave's 32 columns

    // B fragment, all K resident: lane l holds B[k][n0+ln] for
    // k = kw*16 + h*8 + j (j=0..7)  => 32 x 8 B = 64 VGPRs.
    const unsigned char* bp = B8 + (size_t)(n0 + ln) * DIM + h * 8;
    long bfrag[32];
#pragma unroll
    for (int kw = 0; kw < 32; kw++)
        bfrag[kw] = *(const long*)(bp + kw * 16);

    const float mb = -0.5f * musq[n0 + ln];

#pragma unroll 1
    for (int c = 0; c < 4; c++) {
        const int mc = m0 + c * 32;
        const unsigned char* ap = A8 + (size_t)(mc + ln) * DIM + h * 8;
        v16f acc = (v16f)0.f;
#pragma unroll
        for (int kw = 0; kw < 32; kw++) {
            long a = *(const long*)(ap + kw * 16);
            acc = __builtin_amdgcn_mfma_f32_32x32x16_fp8_fp8(
                a, bfrag[kw], acc, 0, 0, 0);
        }
        // Epilogue. C/D layout (m74/m101, dtype-indep): col = l&31,
        // row = (reg&3) + 8*(reg>>2) + 4*(l>>5).
#pragma unroll
        for (int r = 0; r < 16; r++) {
            const int rl = (r & 3) + 8 * (r >> 2) + 4 * h;
            const float xb = -0.5f * xsq[mc + rl];   // uniform per half-wave
            float v = __expf(acc[r] + xb + mb);
            __builtin_nontemporal_store(
                v, out + (size_t)(mc + rl) * UNITS + n0 + ln);
        }
    }
}

extern "C" void kernel_launch(void* const* d_in, const int* in_sizes, int n_in,
                              void* d_out, int out_size, void* d_ws, size_t ws_size,
                              hipStream_t stream) {
    const float* inputs = (const float*)d_in[0];   // [16384, 512] fp32
    const float* mu     = (const float*)d_in[1];   // [512, 1024] fp32
    float* out = (float*)d_out;                    // [16384, 1024] fp32

    char* ws = (char*)d_ws;
    unsigned char* A8 = (unsigned char*)ws;                            // 8 MiB
    unsigned char* B8 = (unsigned char*)(ws + (size_t)BATCH * DIM);    // 512 KiB
    float* xsq  = (float*)(ws + (size_t)BATCH * DIM + (size_t)UNITS * DIM);
    float* musq = xsq + BATCH;

    prep_kernel<<<BATCH / 4 + UNITS / 64, 256, 0, stream>>>(
        inputs, mu, A8, B8, xsq, musq);
    rbf_gemm_kernel<<<1024, 256, 0, stream>>>(A8, B8, xsq, musq, out);
}

// Round 6
// 116.559 us; speedup vs baseline: 1.4374x; 1.4374x over previous
//
#include <hip/hip_runtime.h>
#include <hip/hip_bf16.h>

#define BATCH 16384
#define DIM   512
#define UNITS 1024
// GAMMA = 0.5 folded into epilogue: out = exp(cross - 0.5*xsq - 0.5*musq)

typedef float v16f __attribute__((ext_vector_type(16)));

#define APITCH 516   // floats; (APITCH/4)%8 odd -> phase-2 b128 reads ~conflict-free
#define BPITCH 33

// Fragment-order prep.
// A8f layout: byte ((chunk*32 + kw)*64 + lane)*8, chunk=row/32, kw=k/16.
//   Lane l holds A[chunk*32 + (l&31)][kw*16 + (l>>5)*8 + 0..7] as fp8 e4m3.
// B8f layout: byte ((ng*32 + kw)*64 + lane)*8, ng = n/32.
//   Lane l holds B[kw*16 + (l>>5)*8 + 0..7][ng*32 + (l&31)].
// => every GEMM operand load is base + lane*8: fully coalesced 512 B.
// xsq/musq computed on ORIGINAL fp32 values.
__global__ __launch_bounds__(256)
void prep_kernel(const float* __restrict__ in, const float* __restrict__ mu,
                 unsigned char* __restrict__ A8f, unsigned char* __restrict__ B8f,
                 float* __restrict__ xsq, float* __restrict__ musq) {
    __shared__ __attribute__((aligned(16))) char smem[512 * BPITCH * 4 + 1024];
    const int t  = threadIdx.x;
    const int l  = t & 63, w = t >> 6;
    const int ln = l & 31, h = l >> 5;

    if (blockIdx.x < BATCH / 32) {
        // ---- A path: one block per 32-row chunk ----
        float* lds = (float*)smem;                       // [32][APITCH]
        float* red = (float*)(smem + 32 * APITCH * 4);   // [32][8]
        const int c = blockIdx.x;
        const float4* src = (const float4*)(in + (size_t)c * 32 * DIM);
        float4* l4 = (float4*)lds;
#pragma unroll
        for (int i = 0; i < 16; i++) {
            const int f = i * 256 + t;                   // float4 id 0..4095
            l4[(f >> 7) * (APITCH / 4) + (f & 127)] = src[f];
        }
        __syncthreads();
        float s = 0.f;
#pragma unroll
        for (int j = 0; j < 8; j++) {
            const int kw = w * 8 + j;
            const float* p = lds + ln * APITCH + kw * 16 + h * 8;
            float4 f0 = *(const float4*)p;
            float4 f1 = *(const float4*)(p + 4);
            s += f0.x * f0.x + f0.y * f0.y + f0.z * f0.z + f0.w * f0.w
               + f1.x * f1.x + f1.y * f1.y + f1.z * f1.z + f1.w * f1.w;
            int lo = __builtin_amdgcn_cvt_pk_fp8_f32(f0.x, f0.y, 0, false);
            lo     = __builtin_amdgcn_cvt_pk_fp8_f32(f0.z, f0.w, lo, true);
            int hi = __builtin_amdgcn_cvt_pk_fp8_f32(f1.x, f1.y, 0, false);
            hi     = __builtin_amdgcn_cvt_pk_fp8_f32(f1.z, f1.w, hi, true);
            *(int2*)(A8f + (((size_t)c * 32 + kw) * 64 + l) * 8) = make_int2(lo, hi);
        }
        red[ln * 8 + w * 2 + h] = s;   // each (row, col-range) summed exactly once
        __syncthreads();
        if (t < 32) {
            float a = 0.f;
#pragma unroll
            for (int i = 0; i < 8; i++) a += red[t * 8 + i];
            xsq[c * 32 + t] = a;
        }
    } else {
        // ---- B path: one block per 32-column group ----
        float* lds = (float*)smem;                       // [512][BPITCH]
        float* red = (float*)(smem + 512 * BPITCH * 4);  // [32][8]
        const int nb = blockIdx.x - BATCH / 32;
        const int n0 = nb * 32;
        const int col = t & 31, kg = t >> 5;
        float s = 0.f;
        for (int i = 0; i < 64; i++) {
            const int k = i * 8 + kg;
            float v = mu[(size_t)k * UNITS + n0 + col];
            s += v * v;
            lds[k * BPITCH + col] = v;
        }
        red[col * 8 + kg] = s;
        __syncthreads();
        if (t < 32) {
            float a = 0.f;
#pragma unroll
            for (int i = 0; i < 8; i++) a += red[t * 8 + i];
            musq[n0 + t] = a;
        }
#pragma unroll
        for (int j = 0; j < 8; j++) {
            const int kw = w * 8 + j;
            const float* p = lds + (kw * 16 + h * 8) * BPITCH + ln;
            float f[8];
#pragma unroll
            for (int i = 0; i < 8; i++) f[i] = p[i * BPITCH];
            int lo = __builtin_amdgcn_cvt_pk_fp8_f32(f[0], f[1], 0, false);
            lo     = __builtin_amdgcn_cvt_pk_fp8_f32(f[2], f[3], lo, true);
            int hi = __builtin_amdgcn_cvt_pk_fp8_f32(f[4], f[5], 0, false);
            hi     = __builtin_amdgcn_cvt_pk_fp8_f32(f[6], f[7], hi, true);
            *(int2*)(B8f + (((size_t)nb * 32 + kw) * 64 + l) * 8) = make_int2(lo, hi);
        }
    }
}

// Barrier-free, LDS-free RBF GEMM on fragment-order fp8.
// 1024 blocks x 4 waves, all independent. Wave: 128 M-rows (4 chunks of 32)
// x 32 N-cols, K=512. kw-outer loop: B loaded once per kw (no 64-reg B
// residency), 4 independent acc chains feed the 8-cyc MFMA pipe. Every
// VMEM op is lane-linear coalesced (the R5 gather is gone). XCD swizzle:
// XCD b&7 owns a 2048-row, 1 MB L2-resident A slice.
__global__ __launch_bounds__(256, 2)
void rbf_gemm_kernel(const unsigned char* __restrict__ A8f,
                     const unsigned char* __restrict__ B8f,
                     const float* __restrict__ xsq,
                     const float* __restrict__ musq,
                     float* __restrict__ out) {
    const int t  = threadIdx.x;
    const int l  = t & 63;
    const int w  = t >> 6;
    const int ln = l & 31;
    const int h  = l >> 5;

    const int b  = blockIdx.x;      // 1024
    const int x  = b & 7;           // XCD (round-robin dispatch)
    const int q  = b >> 3;
    const int rg = q & 15;          // row-tile within XCD slice
    const int cg = q >> 4;          // 0..7
    const int m0 = x * 2048 + rg * 128;
    const int ng = cg * 4 + w;      // wave's 32-column group (0..31)
    const int chunk0 = m0 >> 5;

    const long* Af = (const long*)A8f + ((size_t)chunk0 * 32) * 64 + l;
    const long* Bf = (const long*)B8f + ((size_t)ng * 32) * 64 + l;

    v16f acc[4];
#pragma unroll
    for (int c = 0; c < 4; c++) acc[c] = (v16f)0.f;

#pragma unroll 8
    for (int kw = 0; kw < 32; kw++) {
        long bk = Bf[kw * 64];
        long a0 = Af[(0 * 32 + kw) * 64];
        long a1 = Af[(1 * 32 + kw) * 64];
        long a2 = Af[(2 * 32 + kw) * 64];
        long a3 = Af[(3 * 32 + kw) * 64];
        acc[0] = __builtin_amdgcn_mfma_f32_32x32x16_fp8_fp8(a0, bk, acc[0], 0, 0, 0);
        acc[1] = __builtin_amdgcn_mfma_f32_32x32x16_fp8_fp8(a1, bk, acc[1], 0, 0, 0);
        acc[2] = __builtin_amdgcn_mfma_f32_32x32x16_fp8_fp8(a2, bk, acc[2], 0, 0, 0);
        acc[3] = __builtin_amdgcn_mfma_f32_32x32x16_fp8_fp8(a3, bk, acc[3], 0, 0, 0);
    }

    // Epilogue. C/D layout (m74/m101, dtype-indep): col = l&31,
    // row = (reg&3) + 8*(reg>>2) + 4*(l>>5).
    const float mb = -0.5f * musq[ng * 32 + ln];
#pragma unroll
    for (int c = 0; c < 4; c++) {
#pragma unroll
        for (int r = 0; r < 16; r++) {
            const int rl  = (r & 3) + 8 * (r >> 2) + 4 * h;
            const int row = m0 + c * 32 + rl;
            float v = __expf(acc[c][r] - 0.5f * xsq[row] + mb);
            __builtin_nontemporal_store(v, out + (size_t)row * UNITS + ng * 32 + ln);
        }
    }
}

extern "C" void kernel_launch(void* const* d_in, const int* in_sizes, int n_in,
                              void* d_out, int out_size, void* d_ws, size_t ws_size,
                              hipStream_t stream) {
    const float* inputs = (const float*)d_in[0];   // [16384, 512] fp32
    const float* mu     = (const float*)d_in[1];   // [512, 1024] fp32
    float* out = (float*)d_out;                    // [16384, 1024] fp32

    char* ws = (char*)d_ws;
    unsigned char* A8f = (unsigned char*)ws;                           // 8 MiB
    unsigned char* B8f = (unsigned char*)(ws + (size_t)BATCH * DIM);   // 512 KiB
    float* xsq  = (float*)(ws + (size_t)BATCH * DIM + (size_t)UNITS * DIM);
    float* musq = xsq + BATCH;

    prep_kernel<<<BATCH / 32 + UNITS / 32, 256, 0, stream>>>(
        inputs, mu, A8f, B8f, xsq, musq);
    rbf_gemm_kernel<<<1024, 256, 0, stream>>>(A8f, B8f, xsq, musq, out);
}